// Round 1
// baseline (192.657 us; speedup 1.0000x reference)
//
#include <hip/hip_runtime.h>
#include <hip/hip_bf16.h>
#include <cstdint>

typedef unsigned short u16;
typedef __bf16 bf16x8 __attribute__((ext_vector_type(8)));
typedef float f32x4 __attribute__((ext_vector_type(4)));

#define BB 8
#define SS 512
#define NN 2048
#define HH 512
#define MM (BB*NN)   // 16384

__device__ inline u16 f2b(float f) {
  __hip_bfloat16 h = __float2bfloat16(f);
  return *reinterpret_cast<u16*>(&h);
}

// ---------- transpose x (B,S,N) -> XR bf16 (B*N, S), plus column sums (mean*S) ----------
__global__ void k_txr(const float* __restrict__ x, u16* __restrict__ xr, float* __restrict__ fv) {
  __shared__ float t[32][33];
  __shared__ float ps[8][32];
  const int b = blockIdx.z, n0 = blockIdx.x * 32, s0 = blockIdx.y * 32;
  const int tx = threadIdx.x, ty = threadIdx.y;
  float acc = 0.f;
  for (int i = ty; i < 32; i += 8) {
    float w = x[(size_t)b*SS*NN + (size_t)(s0+i)*NN + (n0+tx)];
    t[i][tx] = w; acc += w;
  }
  ps[ty][tx] = acc;
  __syncthreads();
  if (ty == 0) {
    float s = 0.f;
    #pragma unroll
    for (int j = 0; j < 8; ++j) s += ps[j][tx];
    atomicAdd(&fv[b*NN + n0 + tx], s);
  }
  for (int i = ty; i < 32; i += 8)
    xr[((size_t)b*NN + (n0+i))*SS + (s0+tx)] = f2b(t[tx][i]);
}

// ---------- per-batch top-9 desc/asc selection, class counts, row flags + degree ----------
__global__ void k_topk(const float* __restrict__ fv, int* __restrict__ meta,
                       int* __restrict__ rowfl, float* __restrict__ degv) {
  const int b = blockIdx.x, tid = threadIdx.x;
  __shared__ float v[NN];
  __shared__ unsigned char taken[NN];
  __shared__ float rv[256]; __shared__ int ri[256];
  __shared__ int sel[18];   // 0..8 desc, 9..17 asc
  __shared__ int scnt[12];  // CP CN CZ | CDp CDn CDz | CAp CAn CAz | CZ8p CZ8n CZ8z
  if (tid < 12) scnt[tid] = 0;
  for (int i = tid; i < NN; i += 256) { v[i] = fv[b*NN + i]; taken[i] = 0; }
  __syncthreads();
  // 9 argmax rounds (value desc, tie -> smaller index)
  for (int r = 0; r < 9; ++r) {
    float bv = -3.4e38f; int bi = 1 << 30;
    for (int i = tid; i < NN; i += 256) {
      if (!taken[i]) { float w = v[i]; if (w > bv || (w == bv && i < bi)) { bv = w; bi = i; } }
    }
    rv[tid] = bv; ri[tid] = bi; __syncthreads();
    for (int st = 128; st > 0; st >>= 1) {
      if (tid < st) { float ov = rv[tid+st]; int oi = ri[tid+st];
        if (ov > rv[tid] || (ov == rv[tid] && oi < ri[tid])) { rv[tid] = ov; ri[tid] = oi; } }
      __syncthreads();
    }
    if (tid == 0) { sel[r] = ri[0]; taken[ri[0]] = 1; }
    __syncthreads();
  }
  for (int i = tid; i < NN; i += 256) taken[i] = 0;
  __syncthreads();
  // 9 argmin rounds (value asc, tie -> smaller index)
  for (int r = 0; r < 9; ++r) {
    float bv = 3.4e38f; int bi = 1 << 30;
    for (int i = tid; i < NN; i += 256) {
      if (!taken[i]) { float w = v[i]; if (w < bv || (w == bv && i < bi)) { bv = w; bi = i; } }
    }
    rv[tid] = bv; ri[tid] = bi; __syncthreads();
    for (int st = 128; st > 0; st >>= 1) {
      if (tid < st) { float ov = rv[tid+st]; int oi = ri[tid+st];
        if (ov < rv[tid] || (ov == rv[tid] && oi < ri[tid])) { rv[tid] = ov; ri[tid] = oi; } }
      __syncthreads();
    }
    if (tid == 0) { sel[9+r] = ri[0]; taken[ri[0]] = 1; }
    __syncthreads();
  }
  // class counts
  int cp = 0, cn = 0, cz = 0;
  for (int i = tid; i < NN; i += 256) { float w = v[i]; cp += (w > 0.f); cn += (w < 0.f); cz += (w == 0.f); }
  ri[tid] = cp; __syncthreads();
  for (int st = 128; st > 0; st >>= 1) { if (tid < st) ri[tid] += ri[tid+st]; __syncthreads(); }
  if (tid == 0) scnt[0] = ri[0];
  __syncthreads();
  ri[tid] = cn; __syncthreads();
  for (int st = 128; st > 0; st >>= 1) { if (tid < st) ri[tid] += ri[tid+st]; __syncthreads(); }
  if (tid == 0) scnt[1] = ri[0];
  __syncthreads();
  ri[tid] = cz; __syncthreads();
  for (int st = 128; st > 0; st >>= 1) { if (tid < st) ri[tid] += ri[tid+st]; __syncthreads(); }
  if (tid == 0) scnt[2] = ri[0];
  __syncthreads();
  if (tid == 0) {
    for (int r = 1; r < 9; ++r) {
      float wD = v[sel[r]];   scnt[3] += (wD > 0.f); scnt[4] += (wD < 0.f); scnt[5] += (wD == 0.f);
      float wA = v[sel[9+r]]; scnt[6] += (wA > 0.f); scnt[7] += (wA < 0.f); scnt[8] += (wA == 0.f);
      float wZ = v[r];        scnt[9] += (wZ > 0.f); scnt[10] += (wZ < 0.f); scnt[11] += (wZ == 0.f);
    }
  }
  __syncthreads();
  const float CP = (float)scnt[0], CN = (float)scnt[1], CZ = (float)scnt[2];
  for (int i = tid; i < NN; i += 256) {
    float w = v[i];
    int cls = (w > 0.f) ? 0 : ((w < 0.f) ? 1 : 2);
    int mD = 0, mA = 0;
    #pragma unroll
    for (int r = 1; r < 9; ++r) { mD |= (sel[r] == i); mA |= (sel[9+r] == i); }
    int mZ8 = (i >= 1 && i <= 8);
    rowfl[b*NN + i] = cls | (mD << 2) | (mA << 3) | (mZ8 << 4);
    float c3 = (mD ? CP : 0.f) + (mA ? CN : 0.f) + (mZ8 ? CZ : 0.f);
    float rp, rn, rz;
    if (cls == 0)      { rp = (float)scnt[3]; rn = (float)scnt[4];  rz = (float)scnt[5];  }
    else if (cls == 1) { rp = (float)scnt[6]; rn = (float)scnt[7];  rz = (float)scnt[8];  }
    else               { rp = (float)scnt[9]; rn = (float)scnt[10]; rz = (float)scnt[11]; }
    float c2 = (rp + rn + rz) - (mD ? rp : 0.f) - (mA ? rn : 0.f) - (mZ8 ? rz : 0.f);
    int cself = (cls == 0 && mD) || (cls == 1 && mA) || (cls == 2 && mZ8);
    degv[b*NN + i] = c3 + c2 + (cself ? 0.f : 1.f);
  }
  if (tid < 18) meta[b*32 + tid] = sel[tid];
  if (tid >= 18 && tid < 30) meta[b*32 + tid] = scnt[tid - 18];
}

// ---------- cast weights to bf16 ----------
__global__ void k_castw(const float* __restrict__ W1, const float* __restrict__ W2,
                        u16* __restrict__ w1b, u16* __restrict__ w2b) {
  int idx = blockIdx.x * 256 + threadIdx.x;
  if (idx < HH*SS) w1b[idx] = f2b(W1[idx]);
  else w2b[idx - HH*SS] = f2b(W2[idx - HH*SS]);
}

// ---------- bf16 GEMM: C(M x 512) = A(M x 512) * Bw(512 x 512)^T + bias ----------
#define GLOAD16(g, l) __builtin_amdgcn_global_load_lds( \
    (const __attribute__((address_space(1))) void*)(g), \
    (__attribute__((address_space(3))) void*)(l), 16, 0, 0)

__global__ __launch_bounds__(256) void k_gemm(const u16* __restrict__ A,
                                              const u16* __restrict__ Bw,
                                              const float* __restrict__ bias,
                                              float* __restrict__ C) {
  __shared__ u16 As[128*32];
  __shared__ u16 Bs[128*32];
  const int tid = threadIdx.x;
  const int w = tid >> 6, l = tid & 63;
  const int wm = w >> 1, wn = w & 1;
  const int m0 = blockIdx.x * 128, n0 = blockIdx.y * 128;
  f32x4 acc[4][4];
  #pragma unroll
  for (int i = 0; i < 4; ++i)
    #pragma unroll
    for (int j = 0; j < 4; ++j) acc[i][j] = (f32x4){0.f, 0.f, 0.f, 0.f};

  const int srow = l >> 2;        // 0..15
  const int skk  = (l & 3) * 8;   // 0,8,16,24

  for (int kt = 0; kt < 512; kt += 32) {
    #pragma unroll
    for (int p = 0; p < 2; ++p) {
      const int q = w*2 + p;
      const u16* ga = A  + (size_t)(m0 + q*16 + srow)*512 + kt + skk;
      GLOAD16(ga, As + q*512);
      const u16* gb = Bw + (size_t)(n0 + q*16 + srow)*512 + kt + skk;
      GLOAD16(gb, Bs + q*512);
    }
    __syncthreads();
    bf16x8 af[4], bfr[4];
    const int lr = l & 15, lk = (l >> 4) * 8;
    #pragma unroll
    for (int i = 0; i < 4; ++i)
      af[i] = *(const bf16x8*)(As + (wm*64 + i*16 + lr)*32 + lk);
    #pragma unroll
    for (int j = 0; j < 4; ++j)
      bfr[j] = *(const bf16x8*)(Bs + (wn*64 + j*16 + lr)*32 + lk);
    #pragma unroll
    for (int i = 0; i < 4; ++i)
      #pragma unroll
      for (int j = 0; j < 4; ++j)
        acc[i][j] = __builtin_amdgcn_mfma_f32_16x16x32_bf16(af[i], bfr[j], acc[i][j], 0, 0, 0);
    __syncthreads();
  }
  const int lr4 = (l >> 4) * 4, lc = l & 15;
  #pragma unroll
  for (int j = 0; j < 4; ++j) {
    const int n = n0 + wn*64 + j*16 + lc;
    const float bv = bias[n];
    #pragma unroll
    for (int i = 0; i < 4; ++i) {
      const int m = m0 + wm*64 + i*16 + lr4;
      #pragma unroll
      for (int r = 0; r < 4; ++r)
        C[(size_t)(m + r)*512 + n] = acc[i][j][r] + bv;
    }
  }
}

// ---------- per-batch sign-class sums of h (atomic partials) ----------
__global__ void k_classsums(const float* __restrict__ h, const int* __restrict__ rowfl,
                            float* __restrict__ sums) {
  const int b = blockIdx.x >> 5, c = blockIdx.x & 31;
  const int d = threadIdx.x;         // 256; handles d and d+256
  const int n0 = c * 64;
  float sp0=0,sn0=0,sz0=0,sp1=0,sn1=0,sz1=0;
  for (int r = 0; r < 64; ++r) {
    const int n = n0 + r;
    const int cls = rowfl[b*NN + n] & 3;
    const float* row = h + ((size_t)b*NN + n)*HH;
    float v0 = row[d], v1 = row[d+256];
    sp0 += (cls==0)?v0:0.f; sn0 += (cls==1)?v0:0.f; sz0 += (cls==2)?v0:0.f;
    sp1 += (cls==0)?v1:0.f; sn1 += (cls==1)?v1:0.f; sz1 += (cls==2)?v1:0.f;
  }
  float* sb = sums + (size_t)b*15*HH;
  atomicAdd(&sb[0*HH+d], sp0); atomicAdd(&sb[0*HH+d+256], sp1);
  atomicAdd(&sb[1*HH+d], sn0); atomicAdd(&sb[1*HH+d+256], sn1);
  atomicAdd(&sb[2*HH+d], sz0); atomicAdd(&sb[2*HH+d+256], sz1);
}

// ---------- per-batch class-filtered set sums over D, A, Z8 ----------
__global__ void k_setsums(const float* __restrict__ h, const int* __restrict__ meta,
                          const int* __restrict__ rowfl, float* __restrict__ sums) {
  const int b = blockIdx.x, d = threadIdx.x;   // 512 threads
  const float* hb = h + (size_t)b*NN*HH;
  const int* mb = meta + b*32;
  float sdp=0,sdn=0,sdz=0, sap=0,san=0,saz=0, szp=0,szn=0,szz=0;
  for (int r = 1; r < 9; ++r) {
    int iD = mb[r];   int cD = rowfl[b*NN+iD] & 3; float vD = hb[(size_t)iD*HH + d];
    sdp += (cD==0)?vD:0.f; sdn += (cD==1)?vD:0.f; sdz += (cD==2)?vD:0.f;
    int iA = mb[9+r]; int cA = rowfl[b*NN+iA] & 3; float vA = hb[(size_t)iA*HH + d];
    sap += (cA==0)?vA:0.f; san += (cA==1)?vA:0.f; saz += (cA==2)?vA:0.f;
    int iZ = r;       int cZ = rowfl[b*NN+iZ] & 3; float vZ = hb[(size_t)iZ*HH + d];
    szp += (cZ==0)?vZ:0.f; szn += (cZ==1)?vZ:0.f; szz += (cZ==2)?vZ:0.f;
  }
  float* sb = sums + (size_t)b*15*HH;
  sb[3*HH+d]=sdp; sb[4*HH+d]=sdn; sb[5*HH+d]=sdz;
  sb[6*HH+d]=sap; sb[7*HH+d]=san; sb[8*HH+d]=saz;
  sb[9*HH+d]=szp; sb[10*HH+d]=szn; sb[11*HH+d]=szz;
}

// ---------- per-row aggregation: out = (C3 + C2 + diag) / deg ; MODE0: relu->bf16, MODE1: f32 ----------
template<int MODE>
__global__ void k_agg(const float* __restrict__ h, const float* __restrict__ sums,
                      const int* __restrict__ rowfl, const float* __restrict__ degv,
                      void* __restrict__ outp) {
  const size_t idx = (size_t)blockIdx.x * 256 + threadIdx.x;   // < MM*HH
  const int d = (int)(idx & 511);
  const size_t row = idx >> 9;
  const int b = (int)(row >> 11);
  const int fl = rowfl[row];
  const int cls = fl & 3;
  const bool mD = fl & 4, mA = fl & 8, mZ8 = fl & 16;
  const float* sb = sums + (size_t)b*15*HH;
  float c3 = (mD ? sb[0*HH+d] : 0.f) + (mA ? sb[1*HH+d] : 0.f) + (mZ8 ? sb[2*HH+d] : 0.f);
  const int rb = (cls == 0) ? 3 : ((cls == 1) ? 6 : 9);
  float rp = sb[(size_t)rb*HH + d], rn = sb[(size_t)(rb+1)*HH + d], rz = sb[(size_t)(rb+2)*HH + d];
  float c2 = (rp + rn + rz) - (mD ? rp : 0.f) - (mA ? rn : 0.f) - (mZ8 ? rz : 0.f);
  const bool cself = (cls == 0 && mD) || (cls == 1 && mA) || (cls == 2 && mZ8);
  float val = c3 + c2 + (cself ? 0.f : h[idx]);
  val /= degv[row];
  if (MODE == 0) { val = fmaxf(val, 0.f); ((u16*)outp)[idx] = f2b(val); }
  else           { ((float*)outp)[idx] = val; }
}

// ---------- transpose (B,N,S) f32 -> (B,S,N) f32 ----------
__global__ void k_tout(const float* __restrict__ a, float* __restrict__ out) {
  __shared__ float t[32][33];
  const int b = blockIdx.z, n0 = blockIdx.x * 32, s0 = blockIdx.y * 32;
  const int tx = threadIdx.x, ty = threadIdx.y;
  for (int i = ty; i < 32; i += 8)
    t[i][tx] = a[((size_t)b*NN + (n0+i))*SS + (s0+tx)];
  __syncthreads();
  for (int i = ty; i < 32; i += 8)
    out[((size_t)b*SS + (s0+i))*NN + (n0+tx)] = t[tx][i];
}

extern "C" void kernel_launch(void* const* d_in, const int* in_sizes, int n_in,
                              void* d_out, int out_size, void* d_ws, size_t ws_size,
                              hipStream_t stream) {
  const float* x  = (const float*)d_in[0];
  const float* W1 = (const float*)d_in[1];
  const float* b1 = (const float*)d_in[2];
  const float* W2 = (const float*)d_in[3];
  const float* b2 = (const float*)d_in[4];
  float* out = (float*)d_out;
  char* ws = (char*)d_ws;

  float* fv    = (float*)(ws + 0);           // 64 KB
  int*   meta  = (int*)  (ws + 65536);       // 1 KB
  int*   rowfl = (int*)  (ws + 66560);       // 64 KB
  float* degv  = (float*)(ws + 132096);      // 64 KB
  float* sums1 = (float*)(ws + 197632);      // 240 KB
  float* sums2 = (float*)(ws + 443392);      // 240 KB
  u16*   w1b   = (u16*)  (ws + 689152);      // 512 KB
  u16*   w2b   = (u16*)  (ws + 1213440);     // 512 KB
  float* bufA  = (float*)(ws + 1737728);     // 32 MB: h1 then h2
  u16*   xrb   = (u16*)  (ws + 35292160);    // 16 MB (bufB lo)
  u16*   g1b   = (u16*)  (ws + 35292160 + 16777216); // 16 MB (bufB hi)
  float* aggo  = (float*)(ws + 35292160);    // 32 MB: reuses whole bufB after gemm2

  hipMemsetAsync(fv, 0, 65536, stream);
  hipMemsetAsync(sums1, 0, 491520, stream);  // sums1 + sums2

  k_txr<<<dim3(NN/32, SS/32, BB), dim3(32, 8), 0, stream>>>(x, xrb, fv);
  k_topk<<<BB, 256, 0, stream>>>(fv, meta, rowfl, degv);
  k_castw<<<2048, 256, 0, stream>>>(W1, W2, w1b, w2b);
  k_gemm<<<dim3(MM/128, 4), 256, 0, stream>>>(xrb, w1b, b1, bufA);
  k_classsums<<<BB*32, 256, 0, stream>>>(bufA, rowfl, sums1);
  k_setsums<<<BB, 512, 0, stream>>>(bufA, meta, rowfl, sums1);
  k_agg<0><<<MM*HH/256, 256, 0, stream>>>(bufA, sums1, rowfl, degv, (void*)g1b);
  k_gemm<<<dim3(MM/128, 4), 256, 0, stream>>>(g1b, w2b, b2, bufA);
  k_classsums<<<BB*32, 256, 0, stream>>>(bufA, rowfl, sums2);
  k_setsums<<<BB, 512, 0, stream>>>(bufA, meta, rowfl, sums2);
  k_agg<1><<<MM*HH/256, 256, 0, stream>>>(bufA, sums2, rowfl, degv, (void*)aggo);
  k_tout<<<dim3(NN/32, SS/32, BB), dim3(32, 8), 0, stream>>>(aggo, out);
}

// Round 2
// 158.238 us; speedup vs baseline: 1.2175x; 1.2175x over previous
//
#include <hip/hip_runtime.h>
#include <hip/hip_bf16.h>
#include <cstdint>

typedef unsigned short u16;
typedef __bf16 bf16x8 __attribute__((ext_vector_type(8)));
typedef float f32x4 __attribute__((ext_vector_type(4)));

#define BB 8
#define SS 512
#define NN 2048
#define HH 512
#define MM (BB*NN)   // 16384

__device__ inline u16 f2b(float f) {
  __hip_bfloat16 h = __float2bfloat16(f);
  return *reinterpret_cast<u16*>(&h);
}

// ---------- transpose x (B,S,N) -> XR bf16 (B*N, S), plus column sums (mean*S) ----------
__global__ void k_txr(const float* __restrict__ x, u16* __restrict__ xr, float* __restrict__ fv) {
  __shared__ float t[32][33];
  __shared__ float ps[8][32];
  const int b = blockIdx.z, n0 = blockIdx.x * 32, s0 = blockIdx.y * 32;
  const int tx = threadIdx.x, ty = threadIdx.y;
  float acc = 0.f;
  for (int i = ty; i < 32; i += 8) {
    float w = x[(size_t)b*SS*NN + (size_t)(s0+i)*NN + (n0+tx)];
    t[i][tx] = w; acc += w;
  }
  ps[ty][tx] = acc;
  __syncthreads();
  if (ty == 0) {
    float s = 0.f;
    #pragma unroll
    for (int j = 0; j < 8; ++j) s += ps[j][tx];
    atomicAdd(&fv[b*NN + n0 + tx], s);
  }
  for (int i = ty; i < 32; i += 8)
    xr[((size_t)b*NN + (n0+i))*SS + (s0+tx)] = f2b(t[tx][i]);
}

// ---------- per-batch top-9 desc/asc selection (register keys), class counts, flags, degree ----------
__global__ __launch_bounds__(256) void k_topk(const float* __restrict__ fv, int* __restrict__ meta,
                       int* __restrict__ rowfl, float* __restrict__ degv) {
  const int b = blockIdx.x, tid = threadIdx.x;
  const int wv = tid >> 6, ln = tid & 63;
  __shared__ float v[NN];
  __shared__ unsigned long long wk[2][4];
  __shared__ unsigned long long winner[2];
  __shared__ int sel[18];
  __shared__ int scnt[12];
  __shared__ int ccnt[3][4];

  float lv[8];
  {
    const float4* fp = (const float4*)(fv + b*NN + tid*8);
    float4 a0 = fp[0], a1 = fp[1];
    lv[0]=a0.x; lv[1]=a0.y; lv[2]=a0.z; lv[3]=a0.w;
    lv[4]=a1.x; lv[5]=a1.y; lv[6]=a1.z; lv[7]=a1.w;
  }
  #pragma unroll
  for (int j = 0; j < 8; ++j) v[tid*8+j] = lv[j];

  unsigned long long kD[8], kA[8];
  #pragma unroll
  for (int j = 0; j < 8; ++j) {
    unsigned u = __float_as_uint(lv[j]);
    u = (u & 0x80000000u) ? ~u : (u | 0x80000000u);
    unsigned idx = (unsigned)(tid*8 + j);
    kD[j] = ((unsigned long long)u << 32) | (0xFFFFFFFFu - idx);
    kA[j] = ((unsigned long long)(~u) << 32) | (0xFFFFFFFFu - idx);
  }
  unsigned mskD = 0, mskA = 0;
  for (int r = 0; r < 9; ++r) {
    unsigned long long bD = 0ull, bA = 0ull;
    #pragma unroll
    for (int j = 0; j < 8; ++j) {
      if (!((mskD >> j) & 1) && kD[j] > bD) bD = kD[j];
      if (!((mskA >> j) & 1) && kA[j] > bA) bA = kA[j];
    }
    #pragma unroll
    for (int o = 32; o > 0; o >>= 1) {
      unsigned long long oD = __shfl_xor(bD, o, 64);
      unsigned long long oA = __shfl_xor(bA, o, 64);
      if (oD > bD) bD = oD;
      if (oA > bA) bA = oA;
    }
    if (ln == 0) { wk[0][wv] = bD; wk[1][wv] = bA; }
    __syncthreads();
    if (tid == 0) {
      unsigned long long mD = wk[0][0], mA = wk[1][0];
      #pragma unroll
      for (int q = 1; q < 4; ++q) {
        if (wk[0][q] > mD) mD = wk[0][q];
        if (wk[1][q] > mA) mA = wk[1][q];
      }
      winner[0] = mD; winner[1] = mA;
      sel[r]   = (int)(0xFFFFFFFFu - (unsigned)mD);
      sel[9+r] = (int)(0xFFFFFFFFu - (unsigned)mA);
    }
    __syncthreads();
    unsigned iD = 0xFFFFFFFFu - (unsigned)winner[0];
    unsigned iA = 0xFFFFFFFFu - (unsigned)winner[1];
    if ((int)(iD >> 3) == tid) mskD |= 1u << (iD & 7);
    if ((int)(iA >> 3) == tid) mskA |= 1u << (iA & 7);
  }

  // class counts from registers
  int cp = 0, cn = 0, cz = 0;
  #pragma unroll
  for (int j = 0; j < 8; ++j) { cp += (lv[j] > 0.f); cn += (lv[j] < 0.f); cz += (lv[j] == 0.f); }
  #pragma unroll
  for (int o = 32; o > 0; o >>= 1) { cp += __shfl_xor(cp, o, 64); cn += __shfl_xor(cn, o, 64); cz += __shfl_xor(cz, o, 64); }
  if (ln == 0) { ccnt[0][wv] = cp; ccnt[1][wv] = cn; ccnt[2][wv] = cz; }
  __syncthreads();
  if (tid == 0) {
    int CP = 0, CN = 0, CZ = 0;
    #pragma unroll
    for (int q = 0; q < 4; ++q) { CP += ccnt[0][q]; CN += ccnt[1][q]; CZ += ccnt[2][q]; }
    scnt[0] = CP; scnt[1] = CN; scnt[2] = CZ;
    for (int t = 3; t < 12; ++t) scnt[t] = 0;
    for (int r = 1; r < 9; ++r) {
      float wD = v[sel[r]];   scnt[3] += (wD > 0.f); scnt[4] += (wD < 0.f); scnt[5] += (wD == 0.f);
      float wA = v[sel[9+r]]; scnt[6] += (wA > 0.f); scnt[7] += (wA < 0.f); scnt[8] += (wA == 0.f);
      float wZ = v[r];        scnt[9] += (wZ > 0.f); scnt[10] += (wZ < 0.f); scnt[11] += (wZ == 0.f);
    }
  }
  __syncthreads();
  const float CP = (float)scnt[0], CN = (float)scnt[1], CZ = (float)scnt[2];
  #pragma unroll
  for (int j = 0; j < 8; ++j) {
    const int i = tid*8 + j;
    float w = lv[j];
    int cls = (w > 0.f) ? 0 : ((w < 0.f) ? 1 : 2);
    int mD = 0, mA = 0;
    #pragma unroll
    for (int r = 1; r < 9; ++r) { mD |= (sel[r] == i); mA |= (sel[9+r] == i); }
    int mZ8 = (i >= 1 && i <= 8);
    rowfl[b*NN + i] = cls | (mD << 2) | (mA << 3) | (mZ8 << 4);
    float c3 = (mD ? CP : 0.f) + (mA ? CN : 0.f) + (mZ8 ? CZ : 0.f);
    float rp, rn, rz;
    if (cls == 0)      { rp = (float)scnt[3]; rn = (float)scnt[4];  rz = (float)scnt[5];  }
    else if (cls == 1) { rp = (float)scnt[6]; rn = (float)scnt[7];  rz = (float)scnt[8];  }
    else               { rp = (float)scnt[9]; rn = (float)scnt[10]; rz = (float)scnt[11]; }
    float c2 = (rp + rn + rz) - (mD ? rp : 0.f) - (mA ? rn : 0.f) - (mZ8 ? rz : 0.f);
    int cself = (cls == 0 && mD) || (cls == 1 && mA) || (cls == 2 && mZ8);
    degv[b*NN + i] = c3 + c2 + (cself ? 0.f : 1.f);
  }
  if (tid < 18) meta[b*32 + tid] = sel[tid];
  if (tid >= 18 && tid < 30) meta[b*32 + tid] = scnt[tid - 18];
}

// ---------- cast weights to bf16 ----------
__global__ void k_castw(const float* __restrict__ W1, const float* __restrict__ W2,
                        u16* __restrict__ w1b, u16* __restrict__ w2b) {
  int idx = blockIdx.x * 256 + threadIdx.x;
  if (idx < HH*SS) w1b[idx] = f2b(W1[idx]);
  else w2b[idx - HH*SS] = f2b(W2[idx - HH*SS]);
}

// ---------- bf16 GEMM: C(M x 512) = A(M x 512) * Bw(512 x 512)^T + bias ----------
#define GLOAD16(g, l) __builtin_amdgcn_global_load_lds( \
    (const __attribute__((address_space(1))) void*)(g), \
    (__attribute__((address_space(3))) void*)(l), 16, 0, 0)

__global__ __launch_bounds__(256) void k_gemm(const u16* __restrict__ A,
                                              const u16* __restrict__ Bw,
                                              const float* __restrict__ bias,
                                              float* __restrict__ C) {
  __shared__ u16 As[128*32];
  __shared__ u16 Bs[128*32];
  const int tid = threadIdx.x;
  const int w = tid >> 6, l = tid & 63;
  const int wm = w >> 1, wn = w & 1;
  const int m0 = blockIdx.x * 128, n0 = blockIdx.y * 128;
  f32x4 acc[4][4];
  #pragma unroll
  for (int i = 0; i < 4; ++i)
    #pragma unroll
    for (int j = 0; j < 4; ++j) acc[i][j] = (f32x4){0.f, 0.f, 0.f, 0.f};

  const int srow = l >> 2;        // 0..15
  const int skk  = (l & 3) * 8;   // 0,8,16,24

  for (int kt = 0; kt < 512; kt += 32) {
    #pragma unroll
    for (int p = 0; p < 2; ++p) {
      const int q = w*2 + p;
      const u16* ga = A  + (size_t)(m0 + q*16 + srow)*512 + kt + skk;
      GLOAD16(ga, As + q*512);
      const u16* gb = Bw + (size_t)(n0 + q*16 + srow)*512 + kt + skk;
      GLOAD16(gb, Bs + q*512);
    }
    __syncthreads();
    bf16x8 af[4], bfr[4];
    const int lr = l & 15, lk = (l >> 4) * 8;
    #pragma unroll
    for (int i = 0; i < 4; ++i)
      af[i] = *(const bf16x8*)(As + (wm*64 + i*16 + lr)*32 + lk);
    #pragma unroll
    for (int j = 0; j < 4; ++j)
      bfr[j] = *(const bf16x8*)(Bs + (wn*64 + j*16 + lr)*32 + lk);
    #pragma unroll
    for (int i = 0; i < 4; ++i)
      #pragma unroll
      for (int j = 0; j < 4; ++j)
        acc[i][j] = __builtin_amdgcn_mfma_f32_16x16x32_bf16(af[i], bfr[j], acc[i][j], 0, 0, 0);
    __syncthreads();
  }
  const int lr4 = (l >> 4) * 4, lc = l & 15;
  #pragma unroll
  for (int j = 0; j < 4; ++j) {
    const int n = n0 + wn*64 + j*16 + lc;
    const float bv = bias[n];
    #pragma unroll
    for (int i = 0; i < 4; ++i) {
      const int m = m0 + wm*64 + i*16 + lr4;
      #pragma unroll
      for (int r = 0; r < 4; ++r)
        C[(size_t)(m + r)*512 + n] = acc[i][j][r] + bv;
    }
  }
}

// ---------- merged class sums (atomic) + set sums ----------
__global__ __launch_bounds__(256) void k_sums(const float* __restrict__ h, const int* __restrict__ meta,
                      const int* __restrict__ rowfl, float* __restrict__ sums) {
  const int b = blockIdx.x / 33, c = blockIdx.x % 33;
  float* sb = sums + (size_t)b*15*HH;
  const int tid = threadIdx.x;
  if (c == 32) {
    const int* mb = meta + b*32;
    const float* hb = h + (size_t)b*NN*HH;
    #pragma unroll
    for (int half = 0; half < 2; ++half) {
      const int d = tid + half*256;
      float sdp=0,sdn=0,sdz=0, sap=0,san=0,saz=0, szp=0,szn=0,szz=0;
      for (int r = 1; r < 9; ++r) {
        int iD = mb[r];   int cD = rowfl[b*NN+iD] & 3; float vD = hb[(size_t)iD*HH + d];
        sdp += (cD==0)?vD:0.f; sdn += (cD==1)?vD:0.f; sdz += (cD==2)?vD:0.f;
        int iA = mb[9+r]; int cA = rowfl[b*NN+iA] & 3; float vA = hb[(size_t)iA*HH + d];
        sap += (cA==0)?vA:0.f; san += (cA==1)?vA:0.f; saz += (cA==2)?vA:0.f;
        int iZ = r;       int cZ = rowfl[b*NN+iZ] & 3; float vZ = hb[(size_t)iZ*HH + d];
        szp += (cZ==0)?vZ:0.f; szn += (cZ==1)?vZ:0.f; szz += (cZ==2)?vZ:0.f;
      }
      sb[3*HH+d]=sdp; sb[4*HH+d]=sdn; sb[5*HH+d]=sdz;
      sb[6*HH+d]=sap; sb[7*HH+d]=san; sb[8*HH+d]=saz;
      sb[9*HH+d]=szp; sb[10*HH+d]=szn; sb[11*HH+d]=szz;
    }
    return;
  }
  const int n0 = c * 64;
  const int fc = tid & 127, rg = tid >> 7;
  f32x4 sp = {0,0,0,0}, sn = {0,0,0,0}, sz = {0,0,0,0};
  for (int it = 0; it < 32; ++it) {
    const int n = n0 + rg + it*2;
    const int cls = rowfl[b*NN + n] & 3;
    const f32x4 hv = *(const f32x4*)(h + ((size_t)b*NN + n)*HH + fc*4);
    if (cls == 0) sp += hv; else if (cls == 1) sn += hv; else sz += hv;
  }
  __shared__ f32x4 red[3][128];
  if (rg == 1) { red[0][fc] = sp; red[1][fc] = sn; red[2][fc] = sz; }
  __syncthreads();
  if (rg == 0) {
    sp += red[0][fc]; sn += red[1][fc]; sz += red[2][fc];
    #pragma unroll
    for (int j = 0; j < 4; ++j) {
      atomicAdd(&sb[0*HH + fc*4 + j], sp[j]);
      atomicAdd(&sb[1*HH + fc*4 + j], sn[j]);
      atomicAdd(&sb[2*HH + fc*4 + j], sz[j]);
    }
  }
}

// ---------- per-row aggregation, layer-1: relu -> bf16, 4-wide ----------
__global__ __launch_bounds__(256) void k_agg0(const float* __restrict__ h, const float* __restrict__ sums,
                      const int* __restrict__ rowfl, const float* __restrict__ degv,
                      u16* __restrict__ outp) {
  const int q = blockIdx.x * 256 + threadIdx.x;   // < MM*HH/4
  const int dd = (q & 127) * 4;
  const int row = q >> 7;
  const int b = row >> 11;
  const int fl = rowfl[row];
  const int cls = fl & 3;
  const float* sb = sums + (size_t)b*15*HH;
  f32x4 c3 = {0,0,0,0};
  if (fl & 4)  c3 += *(const f32x4*)(sb + 0*HH + dd);
  if (fl & 8)  c3 += *(const f32x4*)(sb + 1*HH + dd);
  if (fl & 16) c3 += *(const f32x4*)(sb + 2*HH + dd);
  const int rb = (cls == 0) ? 3 : ((cls == 1) ? 6 : 9);
  f32x4 rp = *(const f32x4*)(sb + rb*HH + dd);
  f32x4 rn = *(const f32x4*)(sb + (rb+1)*HH + dd);
  f32x4 rz = *(const f32x4*)(sb + (rb+2)*HH + dd);
  f32x4 c2 = rp + rn + rz;
  if (fl & 4)  c2 -= rp;
  if (fl & 8)  c2 -= rn;
  if (fl & 16) c2 -= rz;
  const bool cself = (cls == 0 && (fl&4)) || (cls == 1 && (fl&8)) || (cls == 2 && (fl&16));
  f32x4 val = c3 + c2;
  if (!cself) val += *(const f32x4*)(h + (size_t)row*HH + dd);
  const float deg = degv[row];
  ushort4 o;
  o.x = f2b(fmaxf(val[0] / deg, 0.f));
  o.y = f2b(fmaxf(val[1] / deg, 0.f));
  o.z = f2b(fmaxf(val[2] / deg, 0.f));
  o.w = f2b(fmaxf(val[3] / deg, 0.f));
  *(ushort4*)(outp + (size_t)row*HH + dd) = o;
}

// ---------- per-row aggregation, layer-2, fused transpose: out (B,S,N) f32 ----------
__global__ void k_aggT(const float* __restrict__ h, const float* __restrict__ sums,
                       const int* __restrict__ rowfl, const float* __restrict__ degv,
                       float* __restrict__ out) {
  __shared__ float t[32][33];
  const int b = blockIdx.z, n0 = blockIdx.x * 32, d0 = blockIdx.y * 32;
  const int tx = threadIdx.x, ty = threadIdx.y;
  const float* sb = sums + (size_t)b*15*HH;
  const int d = d0 + tx;
  const float s0 = sb[0*HH+d], s1 = sb[1*HH+d], s2 = sb[2*HH+d];
  float cs[9];
  #pragma unroll
  for (int c = 0; c < 9; ++c) cs[c] = sb[(3+c)*HH + d];
  for (int i = ty; i < 32; i += 8) {
    const int row = b*NN + n0 + i;
    const int fl = rowfl[row];
    const int cls = fl & 3;
    float c3 = ((fl&4) ? s0 : 0.f) + ((fl&8) ? s1 : 0.f) + ((fl&16) ? s2 : 0.f);
    const int rb = cls * 3;
    float rp = cs[rb], rn = cs[rb+1], rz = cs[rb+2];
    float c2 = rp + rn + rz - ((fl&4) ? rp : 0.f) - ((fl&8) ? rn : 0.f) - ((fl&16) ? rz : 0.f);
    const bool cself = (cls == 0 && (fl&4)) || (cls == 1 && (fl&8)) || (cls == 2 && (fl&16));
    float val = c3 + c2 + (cself ? 0.f : h[(size_t)row*HH + d]);
    t[i][tx] = val / degv[row];
  }
  __syncthreads();
  for (int i = ty; i < 32; i += 8)
    out[((size_t)b*SS + d0 + i)*NN + n0 + tx] = t[tx][i];
}

extern "C" void kernel_launch(void* const* d_in, const int* in_sizes, int n_in,
                              void* d_out, int out_size, void* d_ws, size_t ws_size,
                              hipStream_t stream) {
  const float* x  = (const float*)d_in[0];
  const float* W1 = (const float*)d_in[1];
  const float* b1 = (const float*)d_in[2];
  const float* W2 = (const float*)d_in[3];
  const float* b2 = (const float*)d_in[4];
  float* out = (float*)d_out;
  char* ws = (char*)d_ws;

  float* fv    = (float*)(ws + 0);           // 64 KB
  int*   meta  = (int*)  (ws + 65536);       // 1 KB
  int*   rowfl = (int*)  (ws + 66560);       // 64 KB
  float* degv  = (float*)(ws + 132096);      // 64 KB
  float* sums1 = (float*)(ws + 197632);      // 240 KB
  float* sums2 = (float*)(ws + 443392);      // 240 KB
  u16*   w1b   = (u16*)  (ws + 689152);      // 512 KB
  u16*   w2b   = (u16*)  (ws + 1213440);     // 512 KB
  float* bufA  = (float*)(ws + 1737728);     // 32 MB: h1 then h2
  u16*   xrb   = (u16*)  (ws + 35292160);    // 16 MB
  u16*   g1b   = (u16*)  (ws + 35292160 + 16777216); // 16 MB

  hipMemsetAsync(fv, 0, 65536, stream);
  hipMemsetAsync(sums1, 0, 491520, stream);  // sums1 + sums2

  k_txr<<<dim3(NN/32, SS/32, BB), dim3(32, 8), 0, stream>>>(x, xrb, fv);
  k_topk<<<BB, 256, 0, stream>>>(fv, meta, rowfl, degv);
  k_castw<<<2048, 256, 0, stream>>>(W1, W2, w1b, w2b);
  k_gemm<<<dim3(MM/128, 4), 256, 0, stream>>>(xrb, w1b, b1, bufA);
  k_sums<<<BB*33, 256, 0, stream>>>(bufA, meta, rowfl, sums1);
  k_agg0<<<MM*HH/4/256, 256, 0, stream>>>(bufA, sums1, rowfl, degv, g1b);
  k_gemm<<<dim3(MM/128, 4), 256, 0, stream>>>(g1b, w2b, b2, bufA);
  k_sums<<<BB*33, 256, 0, stream>>>(bufA, meta, rowfl, sums2);
  k_aggT<<<dim3(NN/32, HH/32, BB), dim3(32, 8), 0, stream>>>(bufA, sums2, rowfl, degv, out);
}